// Round 23
// baseline (104.218 us; speedup 1.0000x reference)
//
#include <hip/hip_runtime.h>
#include <math.h>

#define B_ 8
#define N_ 2048
#define H_ 256

typedef double d4 __attribute__((ext_vector_type(4)));

// One-shot: W1T[k][o] = W1[o][k] (f32). Consecutive lanes read consecutive
// o -> coalesced (r19 lesson: lane coalescing beats per-lane load width).
__global__ __launch_bounds__(256)
void transpose_w1(const float* __restrict__ W1, float* __restrict__ W1T) {
    W1T[(size_t)blockIdx.x * H_ + threadIdx.x] =
        W1[(size_t)threadIdx.x * H_ + blockIdx.x];
}

// In-kernel probe of the v_mfma_f64_16x16x4_f64 lane mapping (~200 cy).
// Rounds 15-18 proved one of vars 1-4 matches on this chip.
__device__ __forceinline__ int self_probe_var() {
    const int l = threadIdx.x & 63;
    d4 z = {0.0, 0.0, 0.0, 0.0};
    d4 r1 = __builtin_amdgcn_mfma_f64_16x16x4f64((double)(l + 1), 1.0, z, 0, 0, 0);
    d4 r2 = __builtin_amdgcn_mfma_f64_16x16x4f64(1.0, (double)(l + 1), z, 0, 0, 0);
    d4 r3 = __builtin_amdgcn_mfma_f64_16x16x4f64((double)(l & 15), 1.0, z, 0, 0, 0);
    const double pw0 = __shfl(r1[0], 0, 64);
    const double pw1 = __shfl(r2[0], 0, 64);
    const double pw2 = __shfl(r3[0], 1, 64);
    const double pw3 = __shfl(r3[2], 16, 64);
    const double pw4 = __shfl(r2[2], 16, 64);
    if (pw0 != 100.0 || pw1 != 100.0) return 0;
    if (pw2 == 0.0 && pw3 == 24.0)  return 1;   // row=4g+v, col=a15
    if (pw2 == 0.0 && pw3 == 36.0)  return 3;   // row=g+4v, col=a15
    if (pw2 == 4.0 && pw4 == 124.0) return 2;   // row=a15,  col=4g+v
    if (pw2 == 4.0 && pw4 == 136.0) return 4;   // row=a15,  col=g+4v
    return 0;
}

// HYBRID s-kernel (round 23): use BOTH pipes at once (m114: MFMA waves and
// VALU waves on a CU co-schedule at max, not sum). Grid 1024; block type
// striped by blockIdx%8 so both types stay co-resident on every CU:
//   slot 0-4 (5/8): MFMA body (r22, verified) -> 640 blocks, rows 0..10239
//   slot 5-7 (3/8): VALU body (r11, verified) -> 384 blocks, rows 10240..16383
// Split ratio from measured standalone rates (315 vs 215 rows/us).
// Probe-fail safety: var==0 -> ALL blocks run the VALU body on blockIdx*16.
__global__ __launch_bounds__(256)
__attribute__((amdgpu_waves_per_eu(2, 4)))
void s_hybrid(const float* __restrict__ hp, const float* __restrict__ W1T,
              const float* __restrict__ b1, const float* __restrict__ w2,
              double* __restrict__ s_out) {
    __shared__ float hs_t[H_][17];              // mfma body staging, 17.4 KB
    __shared__ double spart[4][16];
    const int var = self_probe_var();
    const int t = threadIdx.x;
    const int lane = t & 63;
    const int wave = __builtin_amdgcn_readfirstlane(t >> 6);

    int mfma_mode, m0;
    if (var != 0) {
        const int grp = blockIdx.x >> 3, slot = blockIdx.x & 7;
        if (slot < 5) { mfma_mode = 1; m0 = (grp * 5 + slot) * 16; }
        else          { mfma_mode = 0; m0 = (640 + grp * 3 + (slot - 5)) * 16; }
    } else {
        mfma_mode = 0;
        m0 = blockIdx.x * 16;
    }

    if (mfma_mode) {
        // ---------- MFMA body (r22, verified): 16 rows, wave = 64-o strip ----------
        const int a15 = lane & 15, g = lane >> 4;
        const int oc = wave * 64;

        #pragma unroll
        for (int i = 0; i < 16; ++i)
            hs_t[t][i] = hp[(size_t)(m0 + i) * H_ + t];
        __syncthreads();

        const float* bp = W1T + (size_t)g * H_ + oc + a15;

        d4 acc[4];
        #pragma unroll
        for (int ot = 0; ot < 4; ++ot) acc[ot] = (d4){0.0, 0.0, 0.0, 0.0};

        float ac[2], an[2];
        float bcv[8], bnv[8];
        ac[0] = hs_t[g][a15];
        ac[1] = hs_t[4 + g][a15];
        #pragma unroll
        for (int ot = 0; ot < 4; ++ot) {
            bcv[ot]     = bp[ot * 16];
            bcv[4 + ot] = bp[4 * H_ + ot * 16];
        }

        for (int kc = 0; kc < H_; kc += 8) {
            const int kn = (kc + 8 < H_) ? (kc + 8) : 0;
            an[0] = hs_t[kn + g][a15];
            an[1] = hs_t[kn + 4 + g][a15];
            #pragma unroll
            for (int ot = 0; ot < 4; ++ot) {
                bnv[ot]     = bp[(size_t)kn * H_ + ot * 16];
                bnv[4 + ot] = bp[(size_t)(kn + 4) * H_ + ot * 16];
            }
            {
                const double a0 = (double)ac[0];
                #pragma unroll
                for (int ot = 0; ot < 4; ++ot)
                    acc[ot] = __builtin_amdgcn_mfma_f64_16x16x4f64(
                        a0, (double)bcv[ot], acc[ot], 0, 0, 0);
            }
            {
                const double a1 = (double)ac[1];
                #pragma unroll
                for (int ot = 0; ot < 4; ++ot)
                    acc[ot] = __builtin_amdgcn_mfma_f64_16x16x4f64(
                        a1, (double)bcv[4 + ot], acc[ot], 0, 0, 0);
            }
            ac[0] = an[0]; ac[1] = an[1];
            #pragma unroll
            for (int q = 0; q < 8; ++q) bcv[q] = bnv[q];
        }

        if (var == 1 || var == 3) {
            double psum[4] = {0.0, 0.0, 0.0, 0.0};
            #pragma unroll
            for (int ot = 0; ot < 4; ++ot) {
                const int o = oc + ot * 16 + a15;
                const double bb = (double)b1[o];
                const double ww = (double)w2[o];
                #pragma unroll
                for (int v = 0; v < 4; ++v) {
                    const double u = acc[ot][v] + bb;
                    psum[v] += ww * (u / (1.0 + exp(-u)));
                }
            }
            #pragma unroll
            for (int v = 0; v < 4; ++v) {
                double x = psum[v];
                x += __shfl_xor(x, 1, 64);
                x += __shfl_xor(x, 2, 64);
                x += __shfl_xor(x, 4, 64);
                x += __shfl_xor(x, 8, 64);
                psum[v] = x;
            }
            if (a15 == 0) {
                #pragma unroll
                for (int v = 0; v < 4; ++v) {
                    const int row = (var == 1) ? (4 * g + v) : (g + 4 * v);
                    spart[wave][row] = psum[v];
                }
            }
        } else {
            double ps = 0.0;
            #pragma unroll
            for (int ot = 0; ot < 4; ++ot)
                #pragma unroll
                for (int v = 0; v < 4; ++v) {
                    const int cv = (var == 2) ? (4 * g + v) : (g + 4 * v);
                    const int o = oc + ot * 16 + cv;
                    const double u = acc[ot][v] + (double)b1[o];
                    ps += (double)w2[o] * (u / (1.0 + exp(-u)));
                }
            ps += __shfl_xor(ps, 16, 64);
            ps += __shfl_xor(ps, 32, 64);
            if (g == 0) spart[wave][a15] = ps;
        }
        __syncthreads();
        if (t < 16)
            s_out[m0 + t] = spart[0][t] + spart[1][t] + spart[2][t] + spart[3][t];
        return;
    }

    // ---------- VALU body (r11, verified): 16 rows, wave = 4 rows x all o ----------
    {
        const int mv0 = m0 + wave * 4;
        const int o0 = lane * 4;
        const float* hr = hp + (size_t)mv0 * H_;
        const float* wp = W1T + o0;

        double acc[4][4];
        #pragma unroll
        for (int j = 0; j < 4; ++j)
            #pragma unroll
            for (int r = 0; r < 4; ++r) acc[j][r] = 0.0;

        float4 wA[8], wB[8];
        float hA[32], hB[32];

        #define VLOADW(dst, kcv)                                              \
            do {                                                              \
                _Pragma("unroll")                                             \
                for (int kk = 0; kk < 8; ++kk)                                \
                    dst[kk] = *reinterpret_cast<const float4*>(               \
                        wp + (size_t)((kcv) + kk) * H_);                      \
            } while (0)

        #define VLOADH(dst, kcv)                                              \
            do {                                                              \
                _Pragma("unroll")                                             \
                for (int r = 0; r < 4; ++r)                                   \
                    _Pragma("unroll")                                         \
                    for (int kk = 0; kk < 8; ++kk)                            \
                        dst[r * 8 + kk] = hr[r * H_ + (kcv) + kk];            \
            } while (0)

        #define VCOMPUTE(wv, hbuf)                                            \
            do {                                                              \
                _Pragma("unroll")                                             \
                for (int kk = 0; kk < 8; ++kk) {                              \
                    const double h0 = (double)hbuf[0 * 8 + kk];               \
                    const double h1 = (double)hbuf[1 * 8 + kk];               \
                    const double h2 = (double)hbuf[2 * 8 + kk];               \
                    const double h3 = (double)hbuf[3 * 8 + kk];               \
                    const double a0 = (double)wv[kk].x;                       \
                    const double a1 = (double)wv[kk].y;                       \
                    const double a2 = (double)wv[kk].z;                       \
                    const double a3 = (double)wv[kk].w;                       \
                    acc[0][0] = fma(a0, h0, acc[0][0]);                       \
                    acc[0][1] = fma(a0, h1, acc[0][1]);                       \
                    acc[0][2] = fma(a0, h2, acc[0][2]);                       \
                    acc[0][3] = fma(a0, h3, acc[0][3]);                       \
                    acc[1][0] = fma(a1, h0, acc[1][0]);                       \
                    acc[1][1] = fma(a1, h1, acc[1][1]);                       \
                    acc[1][2] = fma(a1, h2, acc[1][2]);                       \
                    acc[1][3] = fma(a1, h3, acc[1][3]);                       \
                    acc[2][0] = fma(a2, h0, acc[2][0]);                       \
                    acc[2][1] = fma(a2, h1, acc[2][1]);                       \
                    acc[2][2] = fma(a2, h2, acc[2][2]);                       \
                    acc[2][3] = fma(a2, h3, acc[2][3]);                       \
                    acc[3][0] = fma(a3, h0, acc[3][0]);                       \
                    acc[3][1] = fma(a3, h1, acc[3][1]);                       \
                    acc[3][2] = fma(a3, h2, acc[3][2]);                       \
                    acc[3][3] = fma(a3, h3, acc[3][3]);                       \
                }                                                             \
            } while (0)

        VLOADW(wA, 0);
        VLOADH(hA, 0);
        for (int kc = 0; kc < H_; kc += 16) {
            VLOADW(wB, kc + 8);
            VLOADH(hB, kc + 8);
            VCOMPUTE(wA, hA);
            if (kc + 16 < H_) {
                VLOADW(wA, kc + 16);
                VLOADH(hA, kc + 16);
            }
            VCOMPUTE(wB, hB);
        }
        #undef VLOADW
        #undef VLOADH
        #undef VCOMPUTE

        const float4 b1v = *reinterpret_cast<const float4*>(b1 + o0);
        const float4 w2v = *reinterpret_cast<const float4*>(w2 + o0);
        double psum[4] = {0.0, 0.0, 0.0, 0.0};
        #define VEPI(j, bc, wc)                                               \
            do {                                                              \
                const double bb = (double)bc, ww = (double)wc;                \
                _Pragma("unroll")                                             \
                for (int r = 0; r < 4; ++r) {                                 \
                    const double u = acc[j][r] + bb;                          \
                    psum[r] += ww * (u / (1.0 + exp(-u)));                    \
                }                                                             \
            } while (0)
        VEPI(0, b1v.x, w2v.x);
        VEPI(1, b1v.y, w2v.y);
        VEPI(2, b1v.z, w2v.z);
        VEPI(3, b1v.w, w2v.w);
        #undef VEPI

        #pragma unroll
        for (int r = 0; r < 4; ++r) {
            double v = psum[r];
            v += __shfl_xor(v, 1, 64);
            v += __shfl_xor(v, 2, 64);
            v += __shfl_xor(v, 4, 64);
            v += __shfl_xor(v, 8, 64);
            v += __shfl_xor(v, 16, 64);
            v += __shfl_xor(v, 32, 64);
            if (lane == 0) s_out[mv0 + r] = v;
        }
    }
}

// Kernel B: out[b,i,j] = (int32)trunc( (s[b,i] - s[b,j]) + b2 )
__global__ __launch_bounds__(256)
void pair_kernel(const double* __restrict__ s, const float* __restrict__ b2p,
                 int* __restrict__ out) {
    const double b2 = (double)b2p[0];
    const unsigned total4 = (unsigned)(B_) * (unsigned)(N_) * (unsigned)(N_) / 4u;
    const unsigned stride = gridDim.x * blockDim.x;
    for (unsigned idx = blockIdx.x * blockDim.x + threadIdx.x; idx < total4;
         idx += stride) {
        const unsigned base = idx * 4u;                 // element index, %4==0
        const unsigned bi  = base >> 22;                // / (N*N), N*N = 2^22
        const unsigned rem = base & ((1u << 22) - 1u);
        const unsigned i   = rem >> 11;                 // / N
        const unsigned j   = rem & (N_ - 1u);
        const double si = s[bi * N_ + i];
        const double* sp = s + bi * N_ + j;             // 32B aligned (j%4==0)
        const double sj0 = sp[0], sj1 = sp[1], sj2 = sp[2], sj3 = sp[3];
        int4 o;
        o.x = (int)trunc((si - sj0) + b2);
        o.y = (int)trunc((si - sj1) + b2);
        o.z = (int)trunc((si - sj2) + b2);
        o.w = (int)trunc((si - sj3) + b2);
        *reinterpret_cast<int4*>(out + base) = o;
    }
}

extern "C" void kernel_launch(void* const* d_in, const int* in_sizes, int n_in,
                              void* d_out, int out_size, void* d_ws, size_t ws_size,
                              hipStream_t stream) {
    const float* hp = (const float*)d_in[0];
    // d_in[1] = node_mask (unused), d_in[2] = n_nodes (unused)
    const float* W1 = (const float*)d_in[3];
    const float* b1 = (const float*)d_in[4];
    const float* w2 = (const float*)d_in[5];
    const float* b2 = (const float*)d_in[6];

    float*  W1T = (float*)d_ws;                                   // 256 KB
    double* s   = (double*)((char*)d_ws + 256 * 1024);            // 128 KB
    int* out = (int*)d_out;

    transpose_w1<<<H_, H_, 0, stream>>>(W1, W1T);
    s_hybrid<<<(B_ * N_) / 16, 256, 0, stream>>>(hp, W1T, b1, w2, s);
    pair_kernel<<<2048, 256, 0, stream>>>(s, b2, out);
}

// Round 24
// 72.784 us; speedup vs baseline: 1.4319x; 1.4319x over previous
//
#include <hip/hip_runtime.h>
#include <math.h>

#define B_ 8
#define N_ 2048
#define H_ 256

typedef double d4 __attribute__((ext_vector_type(4)));

// One-shot: W1T[k][o] = W1[o][k] (f32). Consecutive lanes read consecutive
// o -> coalesced (r19 lesson: lane coalescing beats per-lane load width).
__global__ __launch_bounds__(256)
void transpose_w1(const float* __restrict__ W1, float* __restrict__ W1T) {
    W1T[(size_t)blockIdx.x * H_ + threadIdx.x] =
        W1[(size_t)threadIdx.x * H_ + blockIdx.x];
}

// In-kernel probe of the v_mfma_f64_16x16x4_f64 lane mapping (~200 cy).
// Rounds 15-22 consistently matched one of vars 1-4 on this chip.
__device__ __forceinline__ int self_probe_var() {
    const int l = threadIdx.x & 63;
    d4 z = {0.0, 0.0, 0.0, 0.0};
    d4 r1 = __builtin_amdgcn_mfma_f64_16x16x4f64((double)(l + 1), 1.0, z, 0, 0, 0);
    d4 r2 = __builtin_amdgcn_mfma_f64_16x16x4f64(1.0, (double)(l + 1), z, 0, 0, 0);
    d4 r3 = __builtin_amdgcn_mfma_f64_16x16x4f64((double)(l & 15), 1.0, z, 0, 0, 0);
    const double pw0 = __shfl(r1[0], 0, 64);
    const double pw1 = __shfl(r2[0], 0, 64);
    const double pw2 = __shfl(r3[0], 1, 64);
    const double pw3 = __shfl(r3[2], 16, 64);
    const double pw4 = __shfl(r2[2], 16, 64);
    if (pw0 != 100.0 || pw1 != 100.0) return 0;
    if (pw2 == 0.0 && pw3 == 24.0)  return 1;   // row=4g+v, col=a15
    if (pw2 == 0.0 && pw3 == 36.0)  return 3;   // row=g+4v, col=a15
    if (pw2 == 4.0 && pw4 == 124.0) return 2;   // row=a15,  col=4g+v
    if (pw2 == 4.0 && pw4 == 136.0) return 4;   // row=a15,  col=g+4v
    return 0;
}

// s-kernel, round 24 = r17's best-known MFMA body (74.6 us total) with the
// VALU fallback merged in as a wave-uniform branch (3 dispatches total
// instead of 4 — harvesting launch overhead, not touching the hot body).
// MFMA path: 32 rows/block, grid 512, 4 waves; wave = 2 m-tiles x 4 o-tiles
// (8 indep acc chains); per 8-k iter: 16 mfma vs 12 coalesced scalar loads,
// one-iteration prefetch. Fallback (var==0, never taken on this chip):
// r12's verified VALU body, wave = 8 rows x all 256 o, acc[4][8].
__global__ __launch_bounds__(256)
__attribute__((amdgpu_waves_per_eu(2, 4)))
void s_kernel(const float* __restrict__ hp, const float* __restrict__ W1T,
              const float* __restrict__ b1, const float* __restrict__ w2,
              double* __restrict__ s_out) {
    __shared__ double spart[4][32];
    const int var = self_probe_var();
    const int t = threadIdx.x;
    const int lane = t & 63;
    const int wave = __builtin_amdgcn_readfirstlane(t >> 6);
    const int m0 = blockIdx.x * 32;

    if (var != 0) {
        // ---------------- MFMA body (r17, verified @74.6) ----------------
        const int a15 = lane & 15, g = lane >> 4;
        const int oc = wave * 64;
        const float* ap0 = hp + (size_t)(m0 + a15) * H_ + g;
        const float* ap1 = ap0 + 16 * H_;
        const float* bp  = W1T + (size_t)g * H_ + oc + a15;

        d4 acc[2][4];
        #pragma unroll
        for (int mt = 0; mt < 2; ++mt)
            #pragma unroll
            for (int ot = 0; ot < 4; ++ot) acc[mt][ot] = (d4){0.0, 0.0, 0.0, 0.0};

        float ac[4], an[4];        // A: [mt*2 + half]
        float bcv[8], bnv[8];      // B: [half*4 + ot]
        ac[0] = ap0[0]; ac[1] = ap0[4]; ac[2] = ap1[0]; ac[3] = ap1[4];
        #pragma unroll
        for (int ot = 0; ot < 4; ++ot) {
            bcv[ot]     = bp[ot * 16];
            bcv[4 + ot] = bp[4 * H_ + ot * 16];
        }

        for (int kc = 0; kc < H_; kc += 8) {
            const int kn = (kc + 8 < H_) ? (kc + 8) : 0;      // guarded prefetch
            an[0] = ap0[kn]; an[1] = ap0[kn + 4];
            an[2] = ap1[kn]; an[3] = ap1[kn + 4];
            #pragma unroll
            for (int ot = 0; ot < 4; ++ot) {
                bnv[ot]     = bp[(size_t)kn * H_ + ot * 16];
                bnv[4 + ot] = bp[(size_t)(kn + 4) * H_ + ot * 16];
            }
            {   // k half 0
                const double a0 = (double)ac[0], a1 = (double)ac[2];
                #pragma unroll
                for (int ot = 0; ot < 4; ++ot) {
                    const double bv = (double)bcv[ot];
                    acc[0][ot] = __builtin_amdgcn_mfma_f64_16x16x4f64(a0, bv, acc[0][ot], 0, 0, 0);
                    acc[1][ot] = __builtin_amdgcn_mfma_f64_16x16x4f64(a1, bv, acc[1][ot], 0, 0, 0);
                }
            }
            {   // k half 1
                const double a0 = (double)ac[1], a1 = (double)ac[3];
                #pragma unroll
                for (int ot = 0; ot < 4; ++ot) {
                    const double bv = (double)bcv[4 + ot];
                    acc[0][ot] = __builtin_amdgcn_mfma_f64_16x16x4f64(a0, bv, acc[0][ot], 0, 0, 0);
                    acc[1][ot] = __builtin_amdgcn_mfma_f64_16x16x4f64(a1, bv, acc[1][ot], 0, 0, 0);
                }
            }
            #pragma unroll
            for (int q = 0; q < 4; ++q) ac[q] = an[q];
            #pragma unroll
            for (int q = 0; q < 8; ++q) bcv[q] = bnv[q];
        }

        if (var == 1 || var == 3) {
            double psum[2][4];
            #pragma unroll
            for (int mt = 0; mt < 2; ++mt)
                #pragma unroll
                for (int v = 0; v < 4; ++v) psum[mt][v] = 0.0;
            #pragma unroll
            for (int ot = 0; ot < 4; ++ot) {
                const int o = oc + ot * 16 + a15;
                const double bb = (double)b1[o];
                const double ww = (double)w2[o];
                #pragma unroll
                for (int mt = 0; mt < 2; ++mt)
                    #pragma unroll
                    for (int v = 0; v < 4; ++v) {
                        const double u = acc[mt][ot][v] + bb;
                        psum[mt][v] += ww * (u / (1.0 + exp(-u)));
                    }
            }
            #pragma unroll
            for (int mt = 0; mt < 2; ++mt)
                #pragma unroll
                for (int v = 0; v < 4; ++v) {
                    double x = psum[mt][v];
                    x += __shfl_xor(x, 1, 64);
                    x += __shfl_xor(x, 2, 64);
                    x += __shfl_xor(x, 4, 64);
                    x += __shfl_xor(x, 8, 64);
                    psum[mt][v] = x;
                }
            if (a15 == 0) {
                #pragma unroll
                for (int mt = 0; mt < 2; ++mt)
                    #pragma unroll
                    for (int v = 0; v < 4; ++v) {
                        const int row = (var == 1) ? (4 * g + v) : (g + 4 * v);
                        spart[wave][mt * 16 + row] = psum[mt][v];
                    }
            }
        } else {
            double ps[2] = {0.0, 0.0};
            #pragma unroll
            for (int ot = 0; ot < 4; ++ot)
                #pragma unroll
                for (int v = 0; v < 4; ++v) {
                    const int cv = (var == 2) ? (4 * g + v) : (g + 4 * v);
                    const int o = oc + ot * 16 + cv;
                    const double bb = (double)b1[o];
                    const double ww = (double)w2[o];
                    #pragma unroll
                    for (int mt = 0; mt < 2; ++mt) {
                        const double u = acc[mt][ot][v] + bb;
                        ps[mt] += ww * (u / (1.0 + exp(-u)));
                    }
                }
            #pragma unroll
            for (int mt = 0; mt < 2; ++mt) {
                ps[mt] += __shfl_xor(ps[mt], 16, 64);
                ps[mt] += __shfl_xor(ps[mt], 32, 64);
            }
            if (g == 0) {
                spart[wave][a15]      = ps[0];
                spart[wave][16 + a15] = ps[1];
            }
        }
        __syncthreads();
        if (t < 32)
            s_out[m0 + t] = spart[0][t] + spart[1][t] + spart[2][t] + spart[3][t];
        return;
    }

    // -------- VALU fallback (r12 verified body): wave = 8 rows x all o --------
    {
        const int mv0 = m0 + wave * 8;
        const int o0 = lane * 4;
        const float* hr = hp + (size_t)mv0 * H_;
        const float* wp = W1T + o0;

        double acc[4][8];
        #pragma unroll
        for (int j = 0; j < 4; ++j)
            #pragma unroll
            for (int r = 0; r < 8; ++r) acc[j][r] = 0.0;

        float4 wA[4], wB[4];
        float hA[32], hB[32];     // 8 rows x 4 k

        #define VLOADW(dst, kcv)                                              \
            do {                                                              \
                _Pragma("unroll")                                             \
                for (int kk = 0; kk < 4; ++kk)                                \
                    dst[kk] = *reinterpret_cast<const float4*>(               \
                        wp + (size_t)((kcv) + kk) * H_);                      \
            } while (0)

        #define VLOADH(dst, kcv)                                              \
            do {                                                              \
                _Pragma("unroll")                                             \
                for (int r = 0; r < 8; ++r)                                   \
                    _Pragma("unroll")                                         \
                    for (int kk = 0; kk < 4; ++kk)                            \
                        dst[r * 4 + kk] = hr[r * H_ + (kcv) + kk];            \
            } while (0)

        #define VCOMPUTE(wv, hbuf)                                            \
            do {                                                              \
                _Pragma("unroll")                                             \
                for (int kk = 0; kk < 4; ++kk) {                              \
                    const double a0 = (double)wv[kk].x;                       \
                    const double a1 = (double)wv[kk].y;                       \
                    const double a2 = (double)wv[kk].z;                       \
                    const double a3 = (double)wv[kk].w;                       \
                    _Pragma("unroll")                                         \
                    for (int r = 0; r < 8; ++r) {                             \
                        const double hv = (double)hbuf[r * 4 + kk];           \
                        acc[0][r] = fma(a0, hv, acc[0][r]);                   \
                        acc[1][r] = fma(a1, hv, acc[1][r]);                   \
                        acc[2][r] = fma(a2, hv, acc[2][r]);                   \
                        acc[3][r] = fma(a3, hv, acc[3][r]);                   \
                    }                                                         \
                }                                                             \
            } while (0)

        VLOADW(wA, 0);
        VLOADH(hA, 0);
        for (int kc = 0; kc < H_; kc += 8) {
            VLOADW(wB, kc + 4);
            VLOADH(hB, kc + 4);
            VCOMPUTE(wA, hA);
            if (kc + 8 < H_) {
                VLOADW(wA, kc + 8);
                VLOADH(hA, kc + 8);
            }
            VCOMPUTE(wB, hB);
        }
        #undef VLOADW
        #undef VLOADH
        #undef VCOMPUTE

        const float4 b1v = *reinterpret_cast<const float4*>(b1 + o0);
        const float4 w2v = *reinterpret_cast<const float4*>(w2 + o0);
        double psum[8] = {0.0, 0.0, 0.0, 0.0, 0.0, 0.0, 0.0, 0.0};
        #define VEPI(j, bc, wc)                                               \
            do {                                                              \
                const double bb = (double)bc, ww = (double)wc;                \
                _Pragma("unroll")                                             \
                for (int r = 0; r < 8; ++r) {                                 \
                    const double u = acc[j][r] + bb;                          \
                    psum[r] += ww * (u / (1.0 + exp(-u)));                    \
                }                                                             \
            } while (0)
        VEPI(0, b1v.x, w2v.x);
        VEPI(1, b1v.y, w2v.y);
        VEPI(2, b1v.z, w2v.z);
        VEPI(3, b1v.w, w2v.w);
        #undef VEPI

        #pragma unroll
        for (int r = 0; r < 8; ++r) {
            double v = psum[r];
            v += __shfl_xor(v, 1, 64);
            v += __shfl_xor(v, 2, 64);
            v += __shfl_xor(v, 4, 64);
            v += __shfl_xor(v, 8, 64);
            v += __shfl_xor(v, 16, 64);
            v += __shfl_xor(v, 32, 64);
            if (lane == 0) s_out[mv0 + r] = v;
        }
    }
}

// Kernel B: out[b,i,j] = (int32)trunc( (s[b,i] - s[b,j]) + b2 )
__global__ __launch_bounds__(256)
void pair_kernel(const double* __restrict__ s, const float* __restrict__ b2p,
                 int* __restrict__ out) {
    const double b2 = (double)b2p[0];
    const unsigned total4 = (unsigned)(B_) * (unsigned)(N_) * (unsigned)(N_) / 4u;
    const unsigned stride = gridDim.x * blockDim.x;
    for (unsigned idx = blockIdx.x * blockDim.x + threadIdx.x; idx < total4;
         idx += stride) {
        const unsigned base = idx * 4u;                 // element index, %4==0
        const unsigned bi  = base >> 22;                // / (N*N), N*N = 2^22
        const unsigned rem = base & ((1u << 22) - 1u);
        const unsigned i   = rem >> 11;                 // / N
        const unsigned j   = rem & (N_ - 1u);
        const double si = s[bi * N_ + i];
        const double* sp = s + bi * N_ + j;             // 32B aligned (j%4==0)
        const double sj0 = sp[0], sj1 = sp[1], sj2 = sp[2], sj3 = sp[3];
        int4 o;
        o.x = (int)trunc((si - sj0) + b2);
        o.y = (int)trunc((si - sj1) + b2);
        o.z = (int)trunc((si - sj2) + b2);
        o.w = (int)trunc((si - sj3) + b2);
        *reinterpret_cast<int4*>(out + base) = o;
    }
}

extern "C" void kernel_launch(void* const* d_in, const int* in_sizes, int n_in,
                              void* d_out, int out_size, void* d_ws, size_t ws_size,
                              hipStream_t stream) {
    const float* hp = (const float*)d_in[0];
    // d_in[1] = node_mask (unused), d_in[2] = n_nodes (unused)
    const float* W1 = (const float*)d_in[3];
    const float* b1 = (const float*)d_in[4];
    const float* w2 = (const float*)d_in[5];
    const float* b2 = (const float*)d_in[6];

    float*  W1T = (float*)d_ws;                                   // 256 KB
    double* s   = (double*)((char*)d_ws + 256 * 1024);            // 128 KB
    int* out = (int*)d_out;

    transpose_w1<<<H_, H_, 0, stream>>>(W1, W1T);
    s_kernel<<<(B_ * N_) / 32, 256, 0, stream>>>(hp, W1T, b1, w2, s);
    pair_kernel<<<2048, 256, 0, stream>>>(s, b2, out);
}